// Round 11
// baseline (294.852 us; speedup 1.0000x reference)
//
#include <hip/hip_runtime.h>
#include <math.h>

#define B 32
#define N 1024
#define W 128
#define R 4
#define EPSC 1e-8f

typedef float f32x4 __attribute__((ext_vector_type(4)));

// ---- ws layout (in floats) ----
#define WS_SUM   0                              // 1 float
#define WS_KSUM  64                             // B*5 softmax denominators
#define WS_BW    256                            // B*16*R*N
#define WS_FW    (WS_BW + B*16*R*N)             // B*R*N
#define WS_ER    (WS_FW + B*R*N)                // B*R*N  exp(cos) read keys
#define WS_EW    (WS_ER + B*R*N)                // B*N    exp(cos*wstr) write key
#define WS_WW    (WS_EW + B*N)                  // B*N

// ---- out offsets (in floats) ----
#define O_RR    0
#define O_MEM   (O_RR + B*R*W)
#define O_LINK  (O_MEM + B*N*W)
#define O_USAGE (O_LINK + B*N*N)
#define O_PREC  (O_USAGE + B*N)
#define O_NRW   (O_PREC + B*N)

#define DOT4(a, bv) ((a).x*(bv).x + (a).y*(bv).y + (a).z*(bv).z + (a).w*(bv).w)

// ===================== K1: cosine scores + exp + partial sums =====================
__global__ void k1_scores(const float* __restrict__ mem,
                          const float* __restrict__ rkeys,
                          const float* __restrict__ wkey,
                          const float* __restrict__ wstr,
                          float* __restrict__ ws) {
    int bx = blockIdx.x;
    int b = bx >> 6;
    int n0 = (bx & 63) << 4;
    int t = threadIdx.x;
    __shared__ float keys[5][W];
    __shared__ float knorm[5];
    __shared__ float epart[5][16];
    for (int idx = t; idx < 5 * W; idx += 256) {
        int r = idx >> 7, w = idx & 127;
        keys[r][w] = (r < 4) ? rkeys[(b * R + r) * W + w] : wkey[b * W + w];
    }
    __syncthreads();
    if (t < 160) {
        int kidx = t >> 5, l = t & 31;
        float s = 0.f;
        #pragma unroll
        for (int c = 0; c < 4; ++c) { float v = keys[kidx][l * 4 + c]; s += v * v; }
        #pragma unroll
        for (int st = 1; st <= 16; st <<= 1) s += __shfl_xor(s, st);
        if (l == 0) knorm[kidx] = sqrtf(s);
    }
    __syncthreads();
    int l16 = t & 15;
    int rloc = t >> 4;          // 0..15
    int n = n0 + rloc;
    const float* mrow = mem + ((size_t)(b * N + n)) * W + l16 * 8;
    float4 a  = *reinterpret_cast<const float4*>(mrow);
    float4 a2 = *reinterpret_cast<const float4*>(mrow + 4);
    float mm = DOT4(a, a) + DOT4(a2, a2);
    float d[5];
    #pragma unroll
    for (int r = 0; r < 5; ++r) {
        float4 k1v = *reinterpret_cast<const float4*>(&keys[r][l16 * 8]);
        float4 k2v = *reinterpret_cast<const float4*>(&keys[r][l16 * 8 + 4]);
        d[r] = DOT4(a, k1v) + DOT4(a2, k2v);
    }
    #pragma unroll
    for (int st = 1; st <= 8; st <<= 1) {
        mm += __shfl_xor(mm, st);
        #pragma unroll
        for (int r = 0; r < 5; ++r) d[r] += __shfl_xor(d[r], st);
    }
    if (l16 == 0) {
        float mn = sqrtf(mm);
        float e[5];
        #pragma unroll
        for (int r = 0; r < 4; ++r) {
            float c = d[r] / fmaxf(knorm[r] * mn, EPSC);
            e[r] = expf(c);
            ws[WS_ER + (b * R + r) * N + n] = e[r];
        }
        float cw = d[4] / fmaxf(knorm[4] * mn, EPSC);
        e[4] = expf(cw * wstr[b]);
        ws[WS_EW + b * N + n] = e[4];
        #pragma unroll
        for (int q = 0; q < 5; ++q) epart[q][rloc] = e[q];
    }
    __syncthreads();
    if (t < 80) {
        int q = t >> 4, i = t & 15;
        float v = epart[q][i];
        #pragma unroll
        for (int st = 1; st <= 8; st <<= 1) v += __shfl_xor(v, st);
        if (i == 0) atomicAdd(&ws[WS_KSUM + b * 5 + q], v);
    }
}

// ===================== K2: allocation cumprod + ww (lightweight) =====================
// grid B, block 1024 (one element per thread).
__global__ void k2_soft(const float* __restrict__ usage,
                        const float* __restrict__ agate,
                        const float* __restrict__ wgate,
                        float* __restrict__ ws) {
    int b = blockIdx.x, t = threadIdx.x;
    int lane = t & 63, wv = t >> 6;       // 16 waves
    __shared__ float wsc[16];
    __shared__ float red[16];

    float sw = ws[WS_KSUM + b * 5 + 4];
    float wcv = ws[WS_EW + b * N + t] / sw;

    // ---- exclusive cumprod scan of usage ----
    float u = usage[b * N + t];
    float incl = u;
    #pragma unroll
    for (int s = 1; s <= 32; s <<= 1) {
        float up = __shfl_up(incl, s);
        if (lane >= s) incl *= up;
    }
    if (lane == 63) wsc[wv] = incl;
    __syncthreads();
    if (t < 16) {
        float v = wsc[t];
        #pragma unroll
        for (int s = 1; s <= 8; s <<= 1) {
            float up = __shfl_up(v, s);
            if (lane >= s) v *= up;
        }
        wsc[t] = v;  // inclusive over waves
    }
    __syncthreads();
    float woff = (wv == 0) ? 1.f : wsc[wv - 1];
    float eu = __shfl_up(incl, 1);
    float excl = (lane == 0 ? 1.f : eu) * woff;
    float alloc = (1.f - u) * excl;

    float wwv = (agate[b] * (alloc - wcv) + wcv) * wgate[b];
    ws[WS_WW + b * N + t] = wwv;

    float s6 = wwv;
    #pragma unroll
    for (int s = 1; s <= 32; s <<= 1) s6 += __shfl_xor(s6, s);
    __syncthreads();
    if (lane == 0) red[wv] = s6;
    __syncthreads();
    if (t == 0) {
        float acc = 0.f;
        for (int w2 = 0; w2 < 16; ++w2) acc += red[w2];
        atomicAdd(&ws[WS_SUM], acc);
    }
}

// ===================== K3: single pass over L (R4 geometry + raw barriers) =====================
// grid B*16 (64-row strips), block 256. Thread owns 4 fixed cols.
// 8-row batched loads; bw register-accumulated; fw via block-wide LDS
// transpose-reduce. Next batch's loads issued BEFORE the barrier; barriers
// are raw s_barrier (first with lgkmcnt(0) only) so in-flight global
// loads AND NT stores are NOT drained per batch (HIP __syncthreads would
// emit s_waitcnt vmcnt(0), stalling on HBM write-ack twice per batch).
__global__ void k3_link(const float* __restrict__ L,
                        const float* __restrict__ rw,
                        const float* __restrict__ prec,
                        float* __restrict__ ws,
                        float* __restrict__ out) {
    int bx = blockIdx.x;
    int b = bx >> 4;
    int strip = bx & 15;
    int i0 = strip << 6;
    int t = threadIdx.x;
    __shared__ float scratch[256][36];   // padded: float4-aligned, low-conflict
    __shared__ float ww_row[64];
    __shared__ float rw_row[R][64];

    if (t < 64) ww_row[t] = ws[WS_WW + b * N + i0 + t];
    for (int idx = t; idx < R * 64; idx += 256) {
        int r = idx >> 6, i = idx & 63;
        rw_row[r][i] = rw[(b * R + r) * N + i0 + i];
    }
    __syncthreads();

    int j0 = 4 * t;
    float4 wwj = *reinterpret_cast<const float4*>(ws + WS_WW + b * N + j0);
    float4 pj  = *reinterpret_cast<const float4*>(prec + b * N + j0);
    float4 rwj[R];
    #pragma unroll
    for (int r = 0; r < R; ++r)
        rwj[r] = *reinterpret_cast<const float4*>(rw + (b * R + r) * N + j0);
    float4 bwa[R];
    #pragma unroll
    for (int r = 0; r < R; ++r) bwa[r] = make_float4(0.f, 0.f, 0.f, 0.f);

    const float* Lr = L + ((size_t)(b * N + i0)) * N + j0;
    float* Or = out + O_LINK + ((size_t)(b * N + i0)) * N + j0;

    int g = t >> 3, kk = t & 7;   // reduce-phase role: output g, reducer kk

    float4 v[8];
#define LOADB(bat)                                                             \
    {                                                                          \
        _Pragma("unroll")                                                      \
        for (int k = 0; k < 8; ++k)                                            \
            v[k] = *reinterpret_cast<const float4*>(                           \
                Lr + (size_t)((bat) * 8 + k) * N);                             \
    }

#define COMPUTE(bat)                                                           \
    {                                                                          \
        _Pragma("unroll")                                                      \
        for (int k = 0; k < 8; ++k) {                                          \
            int row = (bat) * 8 + k;                                           \
            float wi = ww_row[row];                                            \
            float c = 1.f - wi;                                                \
            f32x4 o;                                                           \
            o.x = (c - wwj.x) * v[k].x + wi * pj.x;                            \
            o.y = (c - wwj.y) * v[k].y + wi * pj.y;                            \
            o.z = (c - wwj.z) * v[k].z + wi * pj.z;                            \
            o.w = (c - wwj.w) * v[k].w + wi * pj.w;                            \
            __builtin_nontemporal_store(o,                                     \
                reinterpret_cast<f32x4*>(Or + (size_t)row * N));               \
            float4 f;                                                          \
            f.x = DOT4(v[k], rwj[0]); f.y = DOT4(v[k], rwj[1]);                \
            f.z = DOT4(v[k], rwj[2]); f.w = DOT4(v[k], rwj[3]);                \
            *reinterpret_cast<float4*>(&scratch[t][k * 4]) = f;                \
            _Pragma("unroll")                                                  \
            for (int r = 0; r < R; ++r) {                                      \
                float q = rw_row[r][row];                                      \
                bwa[r].x += q * v[k].x; bwa[r].y += q * v[k].y;                \
                bwa[r].z += q * v[k].z; bwa[r].w += q * v[k].w;                \
            }                                                                  \
        }                                                                      \
    }

// barrier 1: scratch ds_writes visible to all waves; do NOT drain vmcnt
#define BAR_LDS() asm volatile("s_waitcnt lgkmcnt(0)\n\ts_barrier" ::: "memory")
// barrier 2: reduce's ds_reads already consumed (data dep) -> bare barrier
#define BAR() asm volatile("s_barrier" ::: "memory")

#define REDUCE(bat)                                                            \
    {                                                                          \
        float s_ = 0.f;                                                        \
        _Pragma("unroll")                                                      \
        for (int m = 0; m < 32; ++m) s_ += scratch[kk + 8 * m][g];             \
        s_ += __shfl_xor(s_, 1);                                               \
        s_ += __shfl_xor(s_, 2);                                               \
        s_ += __shfl_xor(s_, 4);                                               \
        if (kk == 0) {                                                         \
            int rowk = g >> 2, r = g & 3;                                      \
            ws[WS_FW + (b * R + r) * N + i0 + (bat) * 8 + rowk] = s_;          \
        }                                                                      \
    }

    LOADB(0);
    COMPUTE(0); LOADB(1); BAR_LDS(); REDUCE(0); BAR();
    COMPUTE(1); LOADB(2); BAR_LDS(); REDUCE(1); BAR();
    COMPUTE(2); LOADB(3); BAR_LDS(); REDUCE(2); BAR();
    COMPUTE(3); LOADB(4); BAR_LDS(); REDUCE(3); BAR();
    COMPUTE(4); LOADB(5); BAR_LDS(); REDUCE(4); BAR();
    COMPUTE(5); LOADB(6); BAR_LDS(); REDUCE(5); BAR();
    COMPUTE(6); LOADB(7); BAR_LDS(); REDUCE(6); BAR();
    COMPUTE(7);           BAR_LDS(); REDUCE(7);

    // bw: per-strip partials to ws (no global atomics)
    float* bwout = ws + WS_BW + (size_t)(b * 16 + strip) * R * N;
    #pragma unroll
    for (int r = 0; r < R; ++r)
        *reinterpret_cast<float4*>(bwout + r * N + j0) = bwa[r];
#undef LOADB
#undef COMPUTE
#undef REDUCE
#undef BAR_LDS
#undef BAR
}

// ===================== K4: finalize =====================
// grid B*16 (64-row chunks), block 256.
__global__ void k4_final(const float* __restrict__ mem,
                         const float* __restrict__ usage,
                         const float* __restrict__ prec,
                         const float* __restrict__ rmodes,
                         const float* __restrict__ rstr,
                         const float* __restrict__ fgates,
                         const float* __restrict__ ev,
                         const float* __restrict__ wvec,
                         float* __restrict__ ws,
                         float* __restrict__ out) {
    int bx = blockIdx.x;
    int b = bx >> 4;
    int n0 = (bx & 15) << 6;
    int t = threadIdx.x;
    __shared__ float nrw[R][64];
    __shared__ float wwl[64];
    __shared__ float rrl[2][R][W];

    // phase 1: new_rw (256 = R*64 work items); content weight finished inline
    {
        int r = t >> 6, nl = t & 63, n = n0 + nl;
        float bs = 0.f;
        #pragma unroll
        for (int tile = 0; tile < 16; ++tile)
            bs += ws[WS_BW + ((size_t)(b * 16 + tile) * R + r) * N + n];
        float fwv = ws[WS_FW + (b * R + r) * N + n];
        float cv  = ws[WS_ER + (b * R + r) * N + n] / ws[WS_KSUM + b * 5 + r]
                    * rstr[b * R + r];
        float m0 = rmodes[(b * R + r) * 3 + 0];
        float m1 = rmodes[(b * R + r) * 3 + 1];
        float m2 = rmodes[(b * R + r) * 3 + 2];
        float v = fwv * m0 + bs * m1 + cv * m2;
        out[O_NRW + (b * R + r) * N + n] = v;
        nrw[r][nl] = v;
    }
    __syncthreads();

    // phase 2: usage_new, precedence_new
    if (t < 64) {
        int n = n0 + t;
        float ret = 1.f;
        #pragma unroll
        for (int r = 0; r < R; ++r) ret *= (1.f - fgates[b * R + r] * nrw[r][t]);
        float u = usage[b * N + n];
        float w = ws[WS_WW + b * N + n];
        out[O_USAGE + b * N + n] = (u + w - u * w) * ret;
        float S = ws[WS_SUM];
        out[O_PREC + b * N + n] = (1.f - S) * prec[b * N + n] + w;
        wwl[t] = w;
    }
    __syncthreads();

    // phase 3: memory_new + read_result partial
    int wi = t & 127, half = t >> 7;
    float er = ev[b * W + wi], wvv = wvec[b * W + wi];
    float acc[R] = {0.f, 0.f, 0.f, 0.f};
    for (int k = 0; k < 32; ++k) {
        int nl = half * 32 + k;
        int n = n0 + nl;
        size_t off = ((size_t)(b * N + n)) * W + wi;
        float m = mem[off];
        float wn = wwl[nl];
        out[O_MEM + off] = m * (1.f - wn * er) + wn * wvv;
        #pragma unroll
        for (int r = 0; r < R; ++r) acc[r] += nrw[r][nl] * m;
    }
    #pragma unroll
    for (int r = 0; r < R; ++r) rrl[half][r][wi] = acc[r];
    __syncthreads();
    for (int idx = t; idx < R * W; idx += 256) {
        int r = idx >> 7, w2 = idx & 127;
        atomicAdd(&out[O_RR + (b * R + r) * W + w2], rrl[0][r][w2] + rrl[1][r][w2]);
    }
}

extern "C" void kernel_launch(void* const* d_in, const int* in_sizes, int n_in,
                              void* d_out, int out_size, void* d_ws, size_t ws_size,
                              hipStream_t stream) {
    const float* mem    = (const float*)d_in[0];
    const float* L      = (const float*)d_in[1];
    const float* usage  = (const float*)d_in[2];
    const float* prec   = (const float*)d_in[3];
    const float* rw     = (const float*)d_in[4];
    const float* rstr   = (const float*)d_in[6];
    const float* rmodes = (const float*)d_in[7];
    const float* wkey   = (const float*)d_in[8];
    const float* rkeys  = (const float*)d_in[5];
    const float* wstr   = (const float*)d_in[9];
    const float* ag     = (const float*)d_in[10];
    const float* wg     = (const float*)d_in[11];
    const float* wv     = (const float*)d_in[12];
    const float* ev     = (const float*)d_in[13];
    const float* fg     = (const float*)d_in[14];
    float* out = (float*)d_out;
    float* ws  = (float*)d_ws;

    (void)hipMemsetAsync(ws, 0, 1024, stream);                               // sum_ww + ksum
    (void)hipMemsetAsync(out, 0, (size_t)B * R * W * sizeof(float), stream); // read_result

    k1_scores<<<B * 64, 256, 0, stream>>>(mem, rkeys, wkey, wstr, ws);
    k2_soft<<<B, 1024, 0, stream>>>(usage, ag, wg, ws);
    k3_link<<<B * 16, 256, 0, stream>>>(L, rw, prec, ws, out);
    k4_final<<<B * 16, 256, 0, stream>>>(mem, usage, prec, rmodes, rstr, fg, ev, wv, ws, out);
}

// Round 12
// 216.832 us; speedup vs baseline: 1.3598x; 1.3598x over previous
//
#include <hip/hip_runtime.h>
#include <math.h>

#define B 32
#define N 1024
#define W 128
#define R 4
#define EPSC 1e-8f

typedef float f32x4 __attribute__((ext_vector_type(4)));

// ---- ws layout (in floats) ----
#define WS_SUM   0                              // 1 float
#define WS_KSUM  64                             // B*5 softmax denominators
#define WS_BW    256                            // B*16*R*N
#define WS_FW    (WS_BW + B*16*R*N)             // B*R*N
#define WS_ER    (WS_FW + B*R*N)                // B*R*N  exp(cos) read keys
#define WS_EW    (WS_ER + B*R*N)                // B*N    exp(cos*wstr) write key
#define WS_WW    (WS_EW + B*N)                  // B*N

// ---- out offsets (in floats) ----
#define O_RR    0
#define O_MEM   (O_RR + B*R*W)
#define O_LINK  (O_MEM + B*N*W)
#define O_USAGE (O_LINK + B*N*N)
#define O_PREC  (O_USAGE + B*N)
#define O_NRW   (O_PREC + B*N)

#define DOT4(a, bv) ((a).x*(bv).x + (a).y*(bv).y + (a).z*(bv).z + (a).w*(bv).w)

// ===================== K1: cosine scores + exp + partial sums =====================
__global__ void k1_scores(const float* __restrict__ mem,
                          const float* __restrict__ rkeys,
                          const float* __restrict__ wkey,
                          const float* __restrict__ wstr,
                          float* __restrict__ ws) {
    int bx = blockIdx.x;
    int b = bx >> 6;
    int n0 = (bx & 63) << 4;
    int t = threadIdx.x;
    __shared__ float keys[5][W];
    __shared__ float knorm[5];
    __shared__ float epart[5][16];
    for (int idx = t; idx < 5 * W; idx += 256) {
        int r = idx >> 7, w = idx & 127;
        keys[r][w] = (r < 4) ? rkeys[(b * R + r) * W + w] : wkey[b * W + w];
    }
    __syncthreads();
    if (t < 160) {
        int kidx = t >> 5, l = t & 31;
        float s = 0.f;
        #pragma unroll
        for (int c = 0; c < 4; ++c) { float v = keys[kidx][l * 4 + c]; s += v * v; }
        #pragma unroll
        for (int st = 1; st <= 16; st <<= 1) s += __shfl_xor(s, st);
        if (l == 0) knorm[kidx] = sqrtf(s);
    }
    __syncthreads();
    int l16 = t & 15;
    int rloc = t >> 4;          // 0..15
    int n = n0 + rloc;
    const float* mrow = mem + ((size_t)(b * N + n)) * W + l16 * 8;
    float4 a  = *reinterpret_cast<const float4*>(mrow);
    float4 a2 = *reinterpret_cast<const float4*>(mrow + 4);
    float mm = DOT4(a, a) + DOT4(a2, a2);
    float d[5];
    #pragma unroll
    for (int r = 0; r < 5; ++r) {
        float4 k1v = *reinterpret_cast<const float4*>(&keys[r][l16 * 8]);
        float4 k2v = *reinterpret_cast<const float4*>(&keys[r][l16 * 8 + 4]);
        d[r] = DOT4(a, k1v) + DOT4(a2, k2v);
    }
    #pragma unroll
    for (int st = 1; st <= 8; st <<= 1) {
        mm += __shfl_xor(mm, st);
        #pragma unroll
        for (int r = 0; r < 5; ++r) d[r] += __shfl_xor(d[r], st);
    }
    if (l16 == 0) {
        float mn = sqrtf(mm);
        float e[5];
        #pragma unroll
        for (int r = 0; r < 4; ++r) {
            float c = d[r] / fmaxf(knorm[r] * mn, EPSC);
            e[r] = expf(c);
            ws[WS_ER + (b * R + r) * N + n] = e[r];
        }
        float cw = d[4] / fmaxf(knorm[4] * mn, EPSC);
        e[4] = expf(cw * wstr[b]);
        ws[WS_EW + b * N + n] = e[4];
        #pragma unroll
        for (int q = 0; q < 5; ++q) epart[q][rloc] = e[q];
    }
    __syncthreads();
    if (t < 80) {
        int q = t >> 4, i = t & 15;
        float v = epart[q][i];
        #pragma unroll
        for (int st = 1; st <= 8; st <<= 1) v += __shfl_xor(v, st);
        if (i == 0) atomicAdd(&ws[WS_KSUM + b * 5 + q], v);
    }
}

// ===================== K2: allocation cumprod + ww (lightweight) =====================
// grid B, block 1024 (one element per thread).
__global__ void k2_soft(const float* __restrict__ usage,
                        const float* __restrict__ agate,
                        const float* __restrict__ wgate,
                        float* __restrict__ ws) {
    int b = blockIdx.x, t = threadIdx.x;
    int lane = t & 63, wv = t >> 6;       // 16 waves
    __shared__ float wsc[16];
    __shared__ float red[16];

    float sw = ws[WS_KSUM + b * 5 + 4];
    float wcv = ws[WS_EW + b * N + t] / sw;

    // ---- exclusive cumprod scan of usage ----
    float u = usage[b * N + t];
    float incl = u;
    #pragma unroll
    for (int s = 1; s <= 32; s <<= 1) {
        float up = __shfl_up(incl, s);
        if (lane >= s) incl *= up;
    }
    if (lane == 63) wsc[wv] = incl;
    __syncthreads();
    if (t < 16) {
        float v = wsc[t];
        #pragma unroll
        for (int s = 1; s <= 8; s <<= 1) {
            float up = __shfl_up(v, s);
            if (lane >= s) v *= up;
        }
        wsc[t] = v;  // inclusive over waves
    }
    __syncthreads();
    float woff = (wv == 0) ? 1.f : wsc[wv - 1];
    float eu = __shfl_up(incl, 1);
    float excl = (lane == 0 ? 1.f : eu) * woff;
    float alloc = (1.f - u) * excl;

    float wwv = (agate[b] * (alloc - wcv) + wcv) * wgate[b];
    ws[WS_WW + b * N + t] = wwv;

    float s6 = wwv;
    #pragma unroll
    for (int s = 1; s <= 32; s <<= 1) s6 += __shfl_xor(s6, s);
    __syncthreads();
    if (lane == 0) red[wv] = s6;
    __syncthreads();
    if (t == 0) {
        float acc = 0.f;
        for (int w2 = 0; w2 < 16; ++w2) acc += red[w2];
        atomicAdd(&ws[WS_SUM], acc);
    }
}

// ===================== K3: single pass over L (v8) =====================
// grid B*16 (64-row strips), block 256, __launch_bounds__(256,2) so the
// allocator may hold the ~110-reg live set (v[8] prefetch across barriers)
// WITHOUT spilling (R10's failure: default 64-VGPR ceiling -> per-batch
// scratch spill, +640 MB HBM). Raw s_barrier (no vmcnt drain) keeps the
// prefetched loads + NT stores in flight across barriers.
__global__ __launch_bounds__(256, 2) void k3_link(
                        const float* __restrict__ L,
                        const float* __restrict__ rw,
                        const float* __restrict__ prec,
                        float* __restrict__ ws,
                        float* __restrict__ out) {
    int bx = blockIdx.x;
    int b = bx >> 4;
    int strip = bx & 15;
    int i0 = strip << 6;
    int t = threadIdx.x;
    __shared__ float scratch[256][36];   // padded: float4-aligned, low-conflict
    __shared__ float ww_row[64];
    __shared__ float rw_row[R][64];

    if (t < 64) ww_row[t] = ws[WS_WW + b * N + i0 + t];
    for (int idx = t; idx < R * 64; idx += 256) {
        int r = idx >> 6, i = idx & 63;
        rw_row[r][i] = rw[(b * R + r) * N + i0 + i];
    }
    __syncthreads();

    int j0 = 4 * t;
    float4 wwj = *reinterpret_cast<const float4*>(ws + WS_WW + b * N + j0);
    float4 pj  = *reinterpret_cast<const float4*>(prec + b * N + j0);
    float4 rwj[R];
    #pragma unroll
    for (int r = 0; r < R; ++r)
        rwj[r] = *reinterpret_cast<const float4*>(rw + (b * R + r) * N + j0);
    float4 bwa[R];
    #pragma unroll
    for (int r = 0; r < R; ++r) bwa[r] = make_float4(0.f, 0.f, 0.f, 0.f);

    const float* Lr = L + ((size_t)(b * N + i0)) * N + j0;
    float* Or = out + O_LINK + ((size_t)(b * N + i0)) * N + j0;

    int g = t >> 3, kk = t & 7;   // reduce-phase role: output g, reducer kk

    float4 v[8];
#define LOADB(bat)                                                             \
    {                                                                          \
        _Pragma("unroll")                                                      \
        for (int k = 0; k < 8; ++k)                                            \
            v[k] = *reinterpret_cast<const float4*>(                           \
                Lr + (size_t)((bat) * 8 + k) * N);                             \
    }

#define COMPUTE(bat)                                                           \
    {                                                                          \
        _Pragma("unroll")                                                      \
        for (int k = 0; k < 8; ++k) {                                          \
            int row = (bat) * 8 + k;                                           \
            float wi = ww_row[row];                                            \
            float c = 1.f - wi;                                                \
            f32x4 o;                                                           \
            o.x = (c - wwj.x) * v[k].x + wi * pj.x;                            \
            o.y = (c - wwj.y) * v[k].y + wi * pj.y;                            \
            o.z = (c - wwj.z) * v[k].z + wi * pj.z;                            \
            o.w = (c - wwj.w) * v[k].w + wi * pj.w;                            \
            __builtin_nontemporal_store(o,                                     \
                reinterpret_cast<f32x4*>(Or + (size_t)row * N));               \
            float4 f;                                                          \
            f.x = DOT4(v[k], rwj[0]); f.y = DOT4(v[k], rwj[1]);                \
            f.z = DOT4(v[k], rwj[2]); f.w = DOT4(v[k], rwj[3]);                \
            *reinterpret_cast<float4*>(&scratch[t][k * 4]) = f;                \
            _Pragma("unroll")                                                  \
            for (int r = 0; r < R; ++r) {                                      \
                float q = rw_row[r][row];                                      \
                bwa[r].x += q * v[k].x; bwa[r].y += q * v[k].y;                \
                bwa[r].z += q * v[k].z; bwa[r].w += q * v[k].w;                \
            }                                                                  \
        }                                                                      \
    }

// barrier 1: scratch ds_writes visible to all waves; do NOT drain vmcnt
#define BAR_LDS() asm volatile("s_waitcnt lgkmcnt(0)\n\ts_barrier" ::: "memory")
// barrier 2: reduce's ds_reads already consumed (data dep) -> bare barrier
#define BAR() asm volatile("s_barrier" ::: "memory")

#define REDUCE(bat)                                                            \
    {                                                                          \
        float s_ = 0.f;                                                        \
        _Pragma("unroll")                                                      \
        for (int m = 0; m < 32; ++m) s_ += scratch[kk + 8 * m][g];             \
        s_ += __shfl_xor(s_, 1);                                               \
        s_ += __shfl_xor(s_, 2);                                               \
        s_ += __shfl_xor(s_, 4);                                               \
        if (kk == 0) {                                                         \
            int rowk = g >> 2, r = g & 3;                                      \
            ws[WS_FW + (b * R + r) * N + i0 + (bat) * 8 + rowk] = s_;          \
        }                                                                      \
    }

    LOADB(0);
    COMPUTE(0); LOADB(1); BAR_LDS(); REDUCE(0); BAR();
    COMPUTE(1); LOADB(2); BAR_LDS(); REDUCE(1); BAR();
    COMPUTE(2); LOADB(3); BAR_LDS(); REDUCE(2); BAR();
    COMPUTE(3); LOADB(4); BAR_LDS(); REDUCE(3); BAR();
    COMPUTE(4); LOADB(5); BAR_LDS(); REDUCE(4); BAR();
    COMPUTE(5); LOADB(6); BAR_LDS(); REDUCE(5); BAR();
    COMPUTE(6); LOADB(7); BAR_LDS(); REDUCE(6); BAR();
    COMPUTE(7);           BAR_LDS(); REDUCE(7);

    // bw: per-strip partials to ws (no global atomics)
    float* bwout = ws + WS_BW + (size_t)(b * 16 + strip) * R * N;
    #pragma unroll
    for (int r = 0; r < R; ++r)
        *reinterpret_cast<float4*>(bwout + r * N + j0) = bwa[r];
#undef LOADB
#undef COMPUTE
#undef REDUCE
#undef BAR_LDS
#undef BAR
}

// ===================== K4: finalize =====================
// grid B*16 (64-row chunks), block 256.
__global__ void k4_final(const float* __restrict__ mem,
                         const float* __restrict__ usage,
                         const float* __restrict__ prec,
                         const float* __restrict__ rmodes,
                         const float* __restrict__ rstr,
                         const float* __restrict__ fgates,
                         const float* __restrict__ ev,
                         const float* __restrict__ wvec,
                         float* __restrict__ ws,
                         float* __restrict__ out) {
    int bx = blockIdx.x;
    int b = bx >> 4;
    int n0 = (bx & 15) << 6;
    int t = threadIdx.x;
    __shared__ float nrw[R][64];
    __shared__ float wwl[64];
    __shared__ float rrl[2][R][W];

    // phase 1: new_rw (256 = R*64 work items); content weight finished inline
    {
        int r = t >> 6, nl = t & 63, n = n0 + nl;
        float bs = 0.f;
        #pragma unroll
        for (int tile = 0; tile < 16; ++tile)
            bs += ws[WS_BW + ((size_t)(b * 16 + tile) * R + r) * N + n];
        float fwv = ws[WS_FW + (b * R + r) * N + n];
        float cv  = ws[WS_ER + (b * R + r) * N + n] / ws[WS_KSUM + b * 5 + r]
                    * rstr[b * R + r];
        float m0 = rmodes[(b * R + r) * 3 + 0];
        float m1 = rmodes[(b * R + r) * 3 + 1];
        float m2 = rmodes[(b * R + r) * 3 + 2];
        float v = fwv * m0 + bs * m1 + cv * m2;
        out[O_NRW + (b * R + r) * N + n] = v;
        nrw[r][nl] = v;
    }
    __syncthreads();

    // phase 2: usage_new, precedence_new
    if (t < 64) {
        int n = n0 + t;
        float ret = 1.f;
        #pragma unroll
        for (int r = 0; r < R; ++r) ret *= (1.f - fgates[b * R + r] * nrw[r][t]);
        float u = usage[b * N + n];
        float w = ws[WS_WW + b * N + n];
        out[O_USAGE + b * N + n] = (u + w - u * w) * ret;
        float S = ws[WS_SUM];
        out[O_PREC + b * N + n] = (1.f - S) * prec[b * N + n] + w;
        wwl[t] = w;
    }
    __syncthreads();

    // phase 3: memory_new + read_result partial
    int wi = t & 127, half = t >> 7;
    float er = ev[b * W + wi], wvv = wvec[b * W + wi];
    float acc[R] = {0.f, 0.f, 0.f, 0.f};
    for (int k = 0; k < 32; ++k) {
        int nl = half * 32 + k;
        int n = n0 + nl;
        size_t off = ((size_t)(b * N + n)) * W + wi;
        float m = mem[off];
        float wn = wwl[nl];
        out[O_MEM + off] = m * (1.f - wn * er) + wn * wvv;
        #pragma unroll
        for (int r = 0; r < R; ++r) acc[r] += nrw[r][nl] * m;
    }
    #pragma unroll
    for (int r = 0; r < R; ++r) rrl[half][r][wi] = acc[r];
    __syncthreads();
    for (int idx = t; idx < R * W; idx += 256) {
        int r = idx >> 7, w2 = idx & 127;
        atomicAdd(&out[O_RR + (b * R + r) * W + w2], rrl[0][r][w2] + rrl[1][r][w2]);
    }
}

extern "C" void kernel_launch(void* const* d_in, const int* in_sizes, int n_in,
                              void* d_out, int out_size, void* d_ws, size_t ws_size,
                              hipStream_t stream) {
    const float* mem    = (const float*)d_in[0];
    const float* L      = (const float*)d_in[1];
    const float* usage  = (const float*)d_in[2];
    const float* prec   = (const float*)d_in[3];
    const float* rw     = (const float*)d_in[4];
    const float* rkeys  = (const float*)d_in[5];
    const float* rstr   = (const float*)d_in[6];
    const float* rmodes = (const float*)d_in[7];
    const float* wkey   = (const float*)d_in[8];
    const float* wstr   = (const float*)d_in[9];
    const float* ag     = (const float*)d_in[10];
    const float* wg     = (const float*)d_in[11];
    const float* wv     = (const float*)d_in[12];
    const float* ev     = (const float*)d_in[13];
    const float* fg     = (const float*)d_in[14];
    float* out = (float*)d_out;
    float* ws  = (float*)d_ws;

    (void)hipMemsetAsync(ws, 0, 1024, stream);                               // sum_ww + ksum
    (void)hipMemsetAsync(out, 0, (size_t)B * R * W * sizeof(float), stream); // read_result

    k1_scores<<<B * 64, 256, 0, stream>>>(mem, rkeys, wkey, wstr, ws);
    k2_soft<<<B, 1024, 0, stream>>>(usage, ag, wg, ws);
    k3_link<<<B * 16, 256, 0, stream>>>(L, rw, prec, ws, out);
    k4_final<<<B * 16, 256, 0, stream>>>(mem, usage, prec, rmodes, rstr, fg, ev, wv, ws, out);
}